// Round 1
// baseline (584.088 us; speedup 1.0000x reference)
//
#include <hip/hip_runtime.h>
#include <hip/hip_bf16.h>

#define BB 8
#define NN 2000
#define VV 2000
#define KK 100
#define EMB 128
#define PENALTY -1e9f

// ---------------------------------------------------------------------------
// Kernel 1: per-row exact top-K (smallest K of V, ascending, ties by index)
// via 4-pass radix select on float bit patterns + 128-wide bitonic sort.
// Emits x_in (= [norm_dist(100), theta_gathered(100), scale(1)]), normalized
// sorted_dist, and the indices.
// ---------------------------------------------------------------------------
__global__ __launch_bounds__(256) void topk_kernel(
    const float* __restrict__ dist, const float* __restrict__ theta,
    const float* __restrict__ scale,
    float* __restrict__ xin, float* __restrict__ sdist, int* __restrict__ idxb)
{
    __shared__ unsigned sh_hist[256];
    __shared__ unsigned long long sh_comp[128];
    __shared__ int sh_tie[64];
    __shared__ unsigned sh_prefix;
    __shared__ int sh_kth, sh_nless, sh_ntie;

    const int row = blockIdx.x;          // 0..B*N-1
    const int t = threadIdx.x;           // 0..255
    const float* drow = dist + (size_t)row * VV;

    unsigned key[8];
#pragma unroll
    for (int j = 0; j < 8; ++j) {
        int e = j * 256 + t;
        key[j] = (e < VV) ? __float_as_uint(drow[e]) : 0xFFFFFFFFu;
    }
    if (t == 0) { sh_prefix = 0u; sh_kth = KK; }

    // 4 radix passes, 8 bits each, MSB first
    for (int p = 0; p < 4; ++p) {
        sh_hist[t] = 0u;
        __syncthreads();
        const int shift = 24 - 8 * p;
        const unsigned pref = sh_prefix;
#pragma unroll
        for (int j = 0; j < 8; ++j) {
            unsigned k = key[j];
            bool ok = (p == 0) || ((k >> (shift + 8)) == pref);
            if (ok) atomicAdd(&sh_hist[(k >> shift) & 255u], 1u);
        }
        __syncthreads();
        if (t == 0) {
            int kth = sh_kth;
            unsigned cum = 0;
            int b = 0;
            for (; b < 256; ++b) {
                unsigned c = sh_hist[b];
                if (cum + c >= (unsigned)kth) break;
                cum += c;
            }
            sh_prefix = (pref << 8) | (unsigned)b;
            sh_kth = kth - (int)cum;
        }
        __syncthreads();
    }

    const unsigned T = sh_prefix;        // exact key of the K-th smallest
    const int need = sh_kth;             // how many ==T elements to take
    if (t == 0) { sh_nless = 0; sh_ntie = 0; }
    __syncthreads();

#pragma unroll
    for (int j = 0; j < 8; ++j) {
        unsigned k = key[j];
        int e = j * 256 + t;
        if (k < T) {
            int p2 = atomicAdd(&sh_nless, 1);
            sh_comp[p2] = ((unsigned long long)k << 32) | (unsigned)e;
        } else if (k == T) {
            int q = atomicAdd(&sh_ntie, 1);
            if (q < 64) sh_tie[q] = e;
        }
    }
    __syncthreads();
    if (t == 0) {
        int nl = sh_nless;               // <= K-1 by construction
        int nt = sh_ntie < 64 ? sh_ntie : 64;
        // sort tie indices ascending (tiny)
        for (int i = 1; i < nt; ++i) {
            int v = sh_tie[i], j2 = i - 1;
            while (j2 >= 0 && sh_tie[j2] > v) { sh_tie[j2 + 1] = sh_tie[j2]; --j2; }
            sh_tie[j2 + 1] = v;
        }
        for (int i = 0; i < need; ++i)
            sh_comp[nl + i] = ((unsigned long long)T << 32) | (unsigned)sh_tie[i];
    }
    __syncthreads();
    if (t >= KK && t < 128) sh_comp[t] = 0xFFFFFFFFFFFFFFFFull;
    __syncthreads();

    // bitonic sort of 128 composite keys (value bits << 32 | index)
    for (int ksz = 2; ksz <= 128; ksz <<= 1) {
        for (int j = ksz >> 1; j > 0; j >>= 1) {
            if (t < 128) {
                int i = t, ix = i ^ j;
                if (ix > i) {
                    unsigned long long a = sh_comp[i], b2 = sh_comp[ix];
                    bool up = ((i & ksz) == 0);
                    if ((a > b2) == up) { sh_comp[i] = b2; sh_comp[ix] = a; }
                }
            }
            __syncthreads();
        }
    }

    const float Tf = __uint_as_float((unsigned)(sh_comp[KK - 1] >> 32));
    const float invT = 1.0f / Tf;
    const float* trow = theta + (size_t)row * VV;
    if (t < KK) {
        unsigned long long c = sh_comp[t];
        unsigned kb = (unsigned)(c >> 32);
        int id = (int)(c & 0xFFFFFFFFu);
        float nv = __uint_as_float(kb) * invT;
        xin[(size_t)row * 201 + t] = nv;
        xin[(size_t)row * 201 + 100 + t] = trow[id];
        sdist[(size_t)row * KK + t] = nv;
        idxb[(size_t)row * KK + t] = id;
    } else if (t == KK) {
        xin[(size_t)row * 201 + 200] = scale[row];
    }
}

// ---------------------------------------------------------------------------
// Generic tiled fp32 GEMM: C[M,Nout] = epilogue(A[M,Kin] @ W[Kin,Nout] + bias)
// BM=64, BN=64, BK=16; 256 threads; 4x4 microtile per thread.
// NORMA: A-element affine transform (InstanceNorm folded): a*sc[b,k]+sh[b,k]
// SUB:   subtract sub[m,Nout] in epilogue (layer 4's - sorted_dist)
// ---------------------------------------------------------------------------
template <bool RELU, bool NORMA, bool SUB>
__global__ __launch_bounds__(256) void gemm_kernel(
    const float* __restrict__ A, const float* __restrict__ W,
    const float* __restrict__ bias, float* __restrict__ C,
    int M, int Kin, int Nout,
    const float* __restrict__ scv, const float* __restrict__ shv,
    const float* __restrict__ sub)
{
    __shared__ float As[16][65];
    __shared__ float Bs[16][65];
    const int m0 = blockIdx.x * 64;
    const int n0 = blockIdx.y * 64;
    const int tid = threadIdx.x;
    const int tx = tid & 15, ty = tid >> 4;

    float acc[4][4] = {};

    for (int k0 = 0; k0 < Kin; k0 += 16) {
        // stage A tile (64 rows x 16 k), transposed into As[k][m]
        for (int l = tid; l < 64 * 16; l += 256) {
            int mm = l >> 4, kk = l & 15;
            int k = k0 + kk, m = m0 + mm;
            float v = 0.f;
            if (k < Kin) {
                v = A[(size_t)m * Kin + k];
                if (NORMA) {
                    int b = m / NN;
                    v = v * scv[b * Kin + k] + shv[b * Kin + k];
                }
            }
            As[kk][mm] = v;
        }
        // stage W tile (16 k x 64 cols)
        for (int l = tid; l < 16 * 64; l += 256) {
            int kk = l >> 6, nn = l & 63;
            int k = k0 + kk, n = n0 + nn;
            Bs[kk][nn] = (k < Kin && n < Nout) ? W[(size_t)k * Nout + n] : 0.f;
        }
        __syncthreads();
#pragma unroll
        for (int kk = 0; kk < 16; ++kk) {
            float a[4], b[4];
#pragma unroll
            for (int i = 0; i < 4; ++i) a[i] = As[kk][ty * 4 + i];
#pragma unroll
            for (int j = 0; j < 4; ++j) b[j] = Bs[kk][tx * 4 + j];
#pragma unroll
            for (int i = 0; i < 4; ++i)
#pragma unroll
                for (int j = 0; j < 4; ++j) acc[i][j] += a[i] * b[j];
        }
        __syncthreads();
    }

#pragma unroll
    for (int i = 0; i < 4; ++i) {
        int m = m0 + ty * 4 + i;
#pragma unroll
        for (int j = 0; j < 4; ++j) {
            int n = n0 + tx * 4 + j;
            if (n < Nout) {
                float v = acc[i][j] + bias[n];
                if (SUB) v -= sub[(size_t)m * Nout + n];
                if (RELU) v = fmaxf(v, 0.f);
                C[(size_t)m * Nout + n] = v;
            }
        }
    }
}

// ---------------------------------------------------------------------------
// InstanceNorm stats: per (b, channel) over the N=2000 axis.
// Emits folded affine: sc = gamma*rsqrt(var+eps), sh = beta - mean*sc.
// ---------------------------------------------------------------------------
__global__ __launch_bounds__(256) void stats_kernel(
    const float* __restrict__ h, const float* __restrict__ gamma,
    const float* __restrict__ beta, float* __restrict__ scv,
    float* __restrict__ shv)
{
    const int b = blockIdx.x;    // 0..7
    const int c = threadIdx.x;   // 0..255
    float sum = 0.f, sumsq = 0.f;
    const float* base = h + (size_t)b * NN * 256 + c;
    for (int n = 0; n < NN; ++n) {
        float v = base[(size_t)n * 256];
        sum += v;
        sumsq += v * v;
    }
    const float inv = 1.0f / (float)NN;
    float mean = sum * inv;
    float var = sumsq * inv - mean * mean;
    float rs = rsqrtf(var + 1e-5f);
    float s = gamma[c] * rs;
    scv[b * 256 + c] = s;
    shv[b * 256 + c] = beta[c] - mean * s;
}

// ---------------------------------------------------------------------------
// Fill row with PENALTY then scatter the K computed values at idx.
// ---------------------------------------------------------------------------
__global__ __launch_bounds__(256) void scatter_kernel(
    const float* __restrict__ out4, const int* __restrict__ idxb,
    float* __restrict__ out)
{
    const int row = blockIdx.x;
    const int t = threadIdx.x;
    float4* orow = (float4*)(out + (size_t)row * VV);
    const float4 pv = make_float4(PENALTY, PENALTY, PENALTY, PENALTY);
    for (int i = t; i < VV / 4; i += 256) orow[i] = pv;
    __syncthreads();
    if (t < KK) {
        int id = idxb[(size_t)row * KK + t];
        out[(size_t)row * VV + id] = out4[(size_t)row * KK + t];
    }
}

extern "C" void kernel_launch(void* const* d_in, const int* in_sizes, int n_in,
                              void* d_out, int out_size, void* d_ws, size_t ws_size,
                              hipStream_t stream)
{
    const float* dist  = (const float*)d_in[0];
    const float* theta = (const float*)d_in[1];
    const float* scale = (const float*)d_in[2];
    const float* w1 = (const float*)d_in[3];
    const float* b1 = (const float*)d_in[4];
    const float* w2 = (const float*)d_in[5];
    const float* b2 = (const float*)d_in[6];
    const float* w3 = (const float*)d_in[7];
    const float* b3 = (const float*)d_in[8];
    const float* w4 = (const float*)d_in[9];
    const float* b4 = (const float*)d_in[10];
    const float* gamma = (const float*)d_in[11];
    const float* beta  = (const float*)d_in[12];
    float* out = (float*)d_out;

    const int M = BB * NN;  // 16000

    // workspace layout (floats)
    float* xin   = (float*)d_ws;                 // M*201
    int*   idxb  = (int*)(xin + (size_t)M * 201);// M*100
    float* sdist = (float*)(idxb + (size_t)M * KK); // M*100
    float* emb1  = sdist + (size_t)M * KK;       // M*128
    float* h     = emb1 + (size_t)M * EMB;       // M*256
    float* emb2  = h + (size_t)M * 2 * EMB;      // M*128
    float* out4  = emb2 + (size_t)M * EMB;       // M*100
    float* scv   = out4 + (size_t)M * KK;        // 8*256
    float* shv   = scv + 8 * 256;                // 8*256

    // 1. top-K + gather + concat
    topk_kernel<<<M, 256, 0, stream>>>(dist, theta, scale, xin, sdist, idxb);

    // 2. layer1: [M,201]@[201,128] + relu
    gemm_kernel<true, false, false><<<dim3(M / 64, 2), 256, 0, stream>>>(
        xin, w1, b1, emb1, M, 201, EMB, nullptr, nullptr, nullptr);

    // 3. layer2: [M,128]@[128,256] + relu
    gemm_kernel<true, false, false><<<dim3(M / 64, 4), 256, 0, stream>>>(
        emb1, w2, b2, h, M, EMB, 2 * EMB, nullptr, nullptr, nullptr);

    // 4. InstanceNorm stats (folded affine)
    stats_kernel<<<BB, 256, 0, stream>>>(h, gamma, beta, scv, shv);

    // 5. layer3: norm(h) @ [256,128] + relu  (norm fused into A-load)
    gemm_kernel<true, true, false><<<dim3(M / 64, 2), 256, 0, stream>>>(
        h, w3, b3, emb2, M, 2 * EMB, EMB, scv, shv, nullptr);

    // 6. layer4: [M,128]@[128,100] - sorted_dist (no relu)
    gemm_kernel<false, false, true><<<dim3(M / 64, 2), 256, 0, stream>>>(
        emb2, w4, b4, out4, M, EMB, KK, nullptr, nullptr, sdist);

    // 7. fill PENALTY + scatter
    scatter_kernel<<<M, 256, 0, stream>>>(out4, idxb, out);
}

// Round 2
// 326.194 us; speedup vs baseline: 1.7906x; 1.7906x over previous
//
#include <hip/hip_runtime.h>
#include <hip/hip_bf16.h>

#define BB 8
#define NN 2000
#define VV 2000
#define KK 100
#define EMB 128
#define PENALTY -1e9f
#define NBIN 2048
#define CAP 160

// ---------------------------------------------------------------------------
// Kernel 1: per-row exact top-K (smallest K of V, ascending, ties by index).
// Fast path: linear-value bucket select (2048 bins, ~1 val/bin for uniform
// data -> conflict-free atomics), parallel prefix scan, rank-by-counting sort.
// Fallback (bucket overflow, never hit on uniform data): raw-bit radix refine.
// ---------------------------------------------------------------------------
__global__ __launch_bounds__(256) void topk_kernel(
    const float* __restrict__ dist, const float* __restrict__ theta,
    const float* __restrict__ scale,
    float* __restrict__ xin, float* __restrict__ sdist, int* __restrict__ idxb)
{
    __shared__ unsigned hist[NBIN];
    __shared__ unsigned long long comp[CAP];
    __shared__ unsigned wsum[4];
    __shared__ int sh_Bt, sh_nless, sh_cnt;
    __shared__ unsigned sh_pref;
    __shared__ int sh_kth, sh_ntie;
    __shared__ int sh_tie[64];
    __shared__ float sh_Tf;

    const int row = blockIdx.x;
    const int t = threadIdx.x;
    const int lane = t & 63, wid = t >> 6;
    const float* drow = dist + (size_t)row * VV;

    // ---- load 8 values/thread, contiguous per thread (2x float4) ----
    unsigned kb[8];
    int bn[8];
    if (t < VV / 8) {
        const float4* d4 = (const float4*)drow;
        float4 a = d4[t * 2], b2 = d4[t * 2 + 1];
        float vv[8] = {a.x, a.y, a.z, a.w, b2.x, b2.y, b2.z, b2.w};
#pragma unroll
        for (int j = 0; j < 8; ++j) {
            kb[j] = __float_as_uint(vv[j]);
            int b = (int)(vv[j] * (float)NBIN);
            bn[j] = b < 0 ? 0 : (b > NBIN - 1 ? NBIN - 1 : b);
        }
    } else {
#pragma unroll
        for (int j = 0; j < 8; ++j) { kb[j] = 0xFFFFFFFFu; bn[j] = NBIN - 1; }
    }

    for (int i = t; i < NBIN; i += 256) hist[i] = 0u;
    if (t == 0) { sh_cnt = 0; sh_ntie = 0; }
    __syncthreads();
#pragma unroll
    for (int j = 0; j < 8; ++j) atomicAdd(&hist[bn[j]], 1u);
    __syncthreads();

    // ---- parallel prefix over 2048 bins: thread t owns bins [8t, 8t+8) ----
    unsigned c8[8], tot = 0;
#pragma unroll
    for (int b = 0; b < 8; ++b) { c8[b] = hist[t * 8 + b]; tot += c8[b]; }
    unsigned incl = tot;
#pragma unroll
    for (int off = 1; off < 64; off <<= 1) {
        unsigned v = __shfl_up(incl, (unsigned)off);
        if (lane >= off) incl += v;
    }
    if (lane == 63) wsum[wid] = incl;
    __syncthreads();
    unsigned woff = 0;
    for (int w = 0; w < wid; ++w) woff += wsum[w];
    unsigned excl = woff + incl - tot;
    if (excl < KK && excl + tot >= KK) {
        unsigned cum = excl;
#pragma unroll
        for (int b = 0; b < 8; ++b) {
            if (cum + c8[b] >= KK) { sh_Bt = t * 8 + b; sh_nless = (int)cum; break; }
            cum += c8[b];
        }
    }
    __syncthreads();
    const int Bt = sh_Bt;

    // ---- compact winners (bin<Bt) + candidates (bin==Bt) ----
#pragma unroll
    for (int j = 0; j < 8; ++j) {
        if (bn[j] <= Bt) {
            int pos = atomicAdd(&sh_cnt, 1);
            if (pos < CAP)
                comp[pos] = ((unsigned long long)kb[j] << 32) | (unsigned)(t * 8 + j);
        }
    }
    __syncthreads();
    int m = sh_cnt;

    if (m > CAP) {
        // ---------- rare fallback: radix-refine the threshold bucket ----------
        __syncthreads();
        if (t == 0) sh_cnt = 0;
        __syncthreads();
#pragma unroll
        for (int j = 0; j < 8; ++j) {
            if (bn[j] < Bt) {
                int pos = atomicAdd(&sh_cnt, 1);
                if (pos < CAP)
                    comp[pos] = ((unsigned long long)kb[j] << 32) | (unsigned)(t * 8 + j);
            }
        }
        __syncthreads();
        if (t == 0) { sh_pref = 0u; sh_kth = KK - sh_nless; }
        __syncthreads();
        for (int p = 0; p < 4; ++p) {
            if (t < 256) hist[t] = 0u;
            __syncthreads();
            const int shift = 24 - 8 * p;
            const unsigned pref = sh_pref;
#pragma unroll
            for (int j = 0; j < 8; ++j) {
                if (bn[j] == Bt) {
                    unsigned k = kb[j];
                    bool ok = (p == 0) || ((k >> (shift + 8)) == pref);
                    if (ok) atomicAdd(&hist[(k >> shift) & 255u], 1u);
                }
            }
            __syncthreads();
            if (t == 0) {
                int kth = sh_kth;
                unsigned cum = 0;
                int b = 0;
                for (; b < 256; ++b) {
                    unsigned c = hist[b];
                    if (cum + c >= (unsigned)kth) break;
                    cum += c;
                }
                sh_pref = (pref << 8) | (unsigned)b;
                sh_kth = kth - (int)cum;
            }
            __syncthreads();
        }
        const unsigned T = sh_pref;
        const int need2 = sh_kth;
#pragma unroll
        for (int j = 0; j < 8; ++j) {
            if (bn[j] == Bt) {
                unsigned k = kb[j];
                if (k < T) {
                    int pos = atomicAdd(&sh_cnt, 1);
                    if (pos < CAP)
                        comp[pos] = ((unsigned long long)k << 32) | (unsigned)(t * 8 + j);
                } else if (k == T) {
                    int q = atomicAdd(&sh_ntie, 1);
                    if (q < 64) sh_tie[q] = t * 8 + j;
                }
            }
        }
        __syncthreads();
        if (t == 0) {
            int nl2 = sh_cnt;
            int nt = sh_ntie < 64 ? sh_ntie : 64;
            for (int i = 1; i < nt; ++i) {
                int v = sh_tie[i], j2 = i - 1;
                while (j2 >= 0 && sh_tie[j2] > v) { sh_tie[j2 + 1] = sh_tie[j2]; --j2; }
                sh_tie[j2 + 1] = v;
            }
            for (int i = 0; i < need2; ++i)
                comp[nl2 + i] = ((unsigned long long)T << 32) | (unsigned)sh_tie[i];
            sh_cnt = nl2 + need2;
        }
        __syncthreads();
        m = sh_cnt;
    }

    // ---- pad + rank-by-counting sort (broadcast LDS reads) ----
    for (int i = m + t; i < CAP; i += 256) comp[i] = ~0ull;
    __syncthreads();
    unsigned long long c = (t < CAP) ? comp[t] : ~0ull;
    int rank = 0;
    if (t < CAP) {
        for (int j = 0; j < CAP; ++j) {
            unsigned long long cj = comp[j];
            rank += (cj < c) || (cj == c && j < t);
        }
        if (rank == KK - 1) sh_Tf = __uint_as_float((unsigned)(c >> 32));
    }
    __syncthreads();
    const float invT = 1.0f / sh_Tf;
    const float* trow = theta + (size_t)row * VV;
    if (t < CAP && rank < KK) {
        unsigned kbits = (unsigned)(c >> 32);
        int id = (int)(c & 0xFFFFFFFFu);
        float nv = __uint_as_float(kbits) * invT;
        xin[(size_t)row * 201 + rank] = nv;
        xin[(size_t)row * 201 + 100 + rank] = trow[id];
        sdist[(size_t)row * KK + rank] = nv;
        idxb[(size_t)row * KK + rank] = id;
    }
    if (t == 255) xin[(size_t)row * 201 + 200] = scale[row];
}

// ---------------------------------------------------------------------------
// Generic tiled fp32 GEMM: C[M,Nout] = epilogue(A[M,Kin] @ W[Kin,Nout] + bias)
// ---------------------------------------------------------------------------
template <bool RELU, bool NORMA, bool SUB>
__global__ __launch_bounds__(256) void gemm_kernel(
    const float* __restrict__ A, const float* __restrict__ W,
    const float* __restrict__ bias, float* __restrict__ C,
    int M, int Kin, int Nout,
    const float* __restrict__ scv, const float* __restrict__ shv,
    const float* __restrict__ sub)
{
    __shared__ float As[16][65];
    __shared__ float Bs[16][65];
    const int m0 = blockIdx.x * 64;
    const int n0 = blockIdx.y * 64;
    const int tid = threadIdx.x;
    const int tx = tid & 15, ty = tid >> 4;

    float acc[4][4] = {};

    for (int k0 = 0; k0 < Kin; k0 += 16) {
        for (int l = tid; l < 64 * 16; l += 256) {
            int mm = l >> 4, kk = l & 15;
            int k = k0 + kk, m = m0 + mm;
            float v = 0.f;
            if (k < Kin) {
                v = A[(size_t)m * Kin + k];
                if (NORMA) {
                    int b = m / NN;
                    v = v * scv[b * Kin + k] + shv[b * Kin + k];
                }
            }
            As[kk][mm] = v;
        }
        for (int l = tid; l < 16 * 64; l += 256) {
            int kk = l >> 6, nn = l & 63;
            int k = k0 + kk, n = n0 + nn;
            Bs[kk][nn] = (k < Kin && n < Nout) ? W[(size_t)k * Nout + n] : 0.f;
        }
        __syncthreads();
#pragma unroll
        for (int kk = 0; kk < 16; ++kk) {
            float a[4], b[4];
#pragma unroll
            for (int i = 0; i < 4; ++i) a[i] = As[kk][ty * 4 + i];
#pragma unroll
            for (int j = 0; j < 4; ++j) b[j] = Bs[kk][tx * 4 + j];
#pragma unroll
            for (int i = 0; i < 4; ++i)
#pragma unroll
                for (int j = 0; j < 4; ++j) acc[i][j] += a[i] * b[j];
        }
        __syncthreads();
    }

#pragma unroll
    for (int i = 0; i < 4; ++i) {
        int m = m0 + ty * 4 + i;
#pragma unroll
        for (int j = 0; j < 4; ++j) {
            int n = n0 + tx * 4 + j;
            if (n < Nout) {
                float v = acc[i][j] + bias[n];
                if (SUB) v -= sub[(size_t)m * Nout + n];
                if (RELU) v = fmaxf(v, 0.f);
                C[(size_t)m * Nout + n] = v;
            }
        }
    }
}

// ---------------------------------------------------------------------------
// InstanceNorm stats, two-phase (parallel over N): partial sums then finalize
// into folded affine sc = gamma*rsqrt(var+eps), sh = beta - mean*sc.
// ---------------------------------------------------------------------------
#define NCHUNK 25
#define CHUNK (NN / NCHUNK)   // 80

__global__ __launch_bounds__(256) void stats_partial(
    const float* __restrict__ h, float* __restrict__ part)
{
    const int b = blockIdx.x, ch = blockIdx.y, c = threadIdx.x;
    const float* base = h + ((size_t)b * NN + (size_t)ch * CHUNK) * 256 + c;
    float s = 0.f, s2 = 0.f;
    for (int n = 0; n < CHUNK; ++n) {
        float v = base[(size_t)n * 256];
        s += v;
        s2 += v * v;
    }
    size_t o = (((size_t)b * NCHUNK + ch) * 256 + c) * 2;
    part[o] = s;
    part[o + 1] = s2;
}

__global__ __launch_bounds__(256) void stats_final(
    const float* __restrict__ part, const float* __restrict__ gamma,
    const float* __restrict__ beta, float* __restrict__ scv,
    float* __restrict__ shv)
{
    const int b = blockIdx.x, c = threadIdx.x;
    float s = 0.f, s2 = 0.f;
    for (int ch = 0; ch < NCHUNK; ++ch) {
        size_t o = (((size_t)b * NCHUNK + ch) * 256 + c) * 2;
        s += part[o];
        s2 += part[o + 1];
    }
    const float inv = 1.0f / (float)NN;
    float mean = s * inv;
    float var = s2 * inv - mean * mean;
    float rs = rsqrtf(var + 1e-5f);
    float sc = gamma[c] * rs;
    scv[b * 256 + c] = sc;
    shv[b * 256 + c] = beta[c] - mean * sc;
}

// ---------------------------------------------------------------------------
// Fill row with PENALTY then scatter the K computed values at idx.
// ---------------------------------------------------------------------------
__global__ __launch_bounds__(256) void scatter_kernel(
    const float* __restrict__ out4, const int* __restrict__ idxb,
    float* __restrict__ out)
{
    const int row = blockIdx.x;
    const int t = threadIdx.x;
    float4* orow = (float4*)(out + (size_t)row * VV);
    const float4 pv = make_float4(PENALTY, PENALTY, PENALTY, PENALTY);
    for (int i = t; i < VV / 4; i += 256) orow[i] = pv;
    __syncthreads();
    if (t < KK) {
        int id = idxb[(size_t)row * KK + t];
        out[(size_t)row * VV + id] = out4[(size_t)row * KK + t];
    }
}

extern "C" void kernel_launch(void* const* d_in, const int* in_sizes, int n_in,
                              void* d_out, int out_size, void* d_ws, size_t ws_size,
                              hipStream_t stream)
{
    const float* dist  = (const float*)d_in[0];
    const float* theta = (const float*)d_in[1];
    const float* scale = (const float*)d_in[2];
    const float* w1 = (const float*)d_in[3];
    const float* b1 = (const float*)d_in[4];
    const float* w2 = (const float*)d_in[5];
    const float* b2 = (const float*)d_in[6];
    const float* w3 = (const float*)d_in[7];
    const float* b3 = (const float*)d_in[8];
    const float* w4 = (const float*)d_in[9];
    const float* b4 = (const float*)d_in[10];
    const float* gamma = (const float*)d_in[11];
    const float* beta  = (const float*)d_in[12];
    float* out = (float*)d_out;

    const int M = BB * NN;  // 16000

    float* xin   = (float*)d_ws;                     // M*201
    int*   idxb  = (int*)(xin + (size_t)M * 201);    // M*100
    float* sdist = (float*)(idxb + (size_t)M * KK);  // M*100
    float* emb1  = sdist + (size_t)M * KK;           // M*128
    float* h     = emb1 + (size_t)M * EMB;           // M*256
    float* emb2  = h + (size_t)M * 2 * EMB;          // M*128
    float* out4  = emb2 + (size_t)M * EMB;           // M*100
    float* scv   = out4 + (size_t)M * KK;            // 8*256
    float* shv   = scv + 8 * 256;                    // 8*256
    float* part  = shv + 8 * 256;                    // 8*25*256*2

    topk_kernel<<<M, 256, 0, stream>>>(dist, theta, scale, xin, sdist, idxb);

    gemm_kernel<true, false, false><<<dim3(M / 64, 2), 256, 0, stream>>>(
        xin, w1, b1, emb1, M, 201, EMB, nullptr, nullptr, nullptr);

    gemm_kernel<true, false, false><<<dim3(M / 64, 4), 256, 0, stream>>>(
        emb1, w2, b2, h, M, EMB, 2 * EMB, nullptr, nullptr, nullptr);

    stats_partial<<<dim3(BB, NCHUNK), 256, 0, stream>>>(h, part);
    stats_final<<<BB, 256, 0, stream>>>(part, gamma, beta, scv, shv);

    gemm_kernel<true, true, false><<<dim3(M / 64, 2), 256, 0, stream>>>(
        h, w3, b3, emb2, M, 2 * EMB, EMB, scv, shv, nullptr);

    gemm_kernel<false, false, true><<<dim3(M / 64, 2), 256, 0, stream>>>(
        emb2, w4, b4, out4, M, EMB, KK, nullptr, nullptr, sdist);

    scatter_kernel<<<M, 256, 0, stream>>>(out4, idxb, out);
}

// Round 3
// 294.268 us; speedup vs baseline: 1.9849x; 1.1085x over previous
//
#include <hip/hip_runtime.h>
#include <hip/hip_bf16.h>

#define BB 8
#define NN 2000
#define VV 2000
#define KK 100
#define EMB 128
#define PENALTY -1e9f
#define NBIN 2048
#define CAP 200

// ---------------------------------------------------------------------------
// Kernel 1: per-row exact top-K (smallest K of V, ascending, ties by index).
// Linear-value buckets (2048 bins), parallel prefix scan -> per-bin start
// offsets, scatter winners to bin-sorted slots, then maxmult+1 odd-even
// passes to fix within-bin order. Radix fallback for pathological rows.
// ---------------------------------------------------------------------------
__global__ __launch_bounds__(256) void topk_kernel(
    const float* __restrict__ dist, const float* __restrict__ theta,
    const float* __restrict__ scale,
    float* __restrict__ xin, float* __restrict__ sdist, int* __restrict__ idxb)
{
    __shared__ unsigned hist[NBIN];              // counts -> start offsets
    __shared__ unsigned long long comp[CAP];
    __shared__ unsigned wsum[4];
    __shared__ int sh_Bt, sh_m, sh_mult;
    __shared__ int sh_cnt, sh_ntie, sh_kth;      // fallback
    __shared__ unsigned sh_pref;
    __shared__ int sh_tie[64];
    __shared__ float sh_Tf;

    const int row = blockIdx.x;
    const int t = threadIdx.x;
    const int lane = t & 63, wid = t >> 6;
    const float* drow = dist + (size_t)row * VV;

    // ---- load 8 values/thread (2x float4), compute linear bins ----
    unsigned kb[8];
    int bn[8];
    if (t < VV / 8) {
        const float4* d4 = (const float4*)drow;
        float4 a = d4[t * 2], b2 = d4[t * 2 + 1];
        float vv[8] = {a.x, a.y, a.z, a.w, b2.x, b2.y, b2.z, b2.w};
#pragma unroll
        for (int j = 0; j < 8; ++j) {
            kb[j] = __float_as_uint(vv[j]);
            int b = (int)(vv[j] * (float)NBIN);
            bn[j] = b < 0 ? 0 : (b > NBIN - 1 ? NBIN - 1 : b);
        }
    } else {
#pragma unroll
        for (int j = 0; j < 8; ++j) { kb[j] = 0xFFFFFFFFu; bn[j] = NBIN - 1; }
    }

    for (int i = t; i < NBIN; i += 256) hist[i] = 0u;
    if (t == 0) { sh_cnt = 0; sh_ntie = 0; sh_mult = 1; }
    __syncthreads();
#pragma unroll
    for (int j = 0; j < 8; ++j) atomicAdd(&hist[bn[j]], 1u);
    __syncthreads();

    // ---- prefix over 2048 bins: thread t owns bins [8t, 8t+8) ----
    unsigned c8[8], tot = 0;
#pragma unroll
    for (int b = 0; b < 8; ++b) { c8[b] = hist[t * 8 + b]; tot += c8[b]; }
    unsigned incl = tot;
#pragma unroll
    for (int off = 1; off < 64; off <<= 1) {
        unsigned v = __shfl_up(incl, (unsigned)off);
        if (lane >= off) incl += v;
    }
    if (lane == 63) wsum[wid] = incl;
    __syncthreads();
    unsigned woff = 0;
    for (int w = 0; w < wid; ++w) woff += wsum[w];
    const unsigned excl = woff + incl - tot;

    // convert own bins to start offsets; find threshold bin
    unsigned run = excl;
#pragma unroll
    for (int b = 0; b < 8; ++b) { unsigned cc = c8[b]; hist[t * 8 + b] = run; run += cc; }
    if (excl < KK && run >= KK) {
        unsigned cum = excl;
#pragma unroll
        for (int b = 0; b < 8; ++b) {
            if (cum + c8[b] >= KK) { sh_Bt = t * 8 + b; sh_m = (int)(cum + c8[b]); break; }
            cum += c8[b];
        }
    }
    __syncthreads();
    const int Bt = sh_Bt;
    const int m = sh_m;

    // max winner-bin multiplicity (for sort pass count)
    {
        int mx = 0;
#pragma unroll
        for (int b = 0; b < 8; ++b)
            if (t * 8 + b <= Bt) mx = mx > (int)c8[b] ? mx : (int)c8[b];
        if (mx > 1) atomicMax(&sh_mult, mx);
    }

    if (m <= CAP) {
        // ---- scatter winners to bin-sorted slots ----
#pragma unroll
        for (int j = 0; j < 8; ++j) {
            if (bn[j] <= Bt) {
                int slot = (int)atomicAdd(&hist[bn[j]], 1u);
                comp[slot] = ((unsigned long long)kb[j] << 32) | (unsigned)(t * 8 + j);
            }
        }
        __syncthreads();
        // ---- odd-even passes fix within-bin order (cross-bin never swaps) ----
        const int passes = (sh_mult > 1) ? sh_mult + 1 : 0;
        for (int p = 0; p < passes; ++p) {
            int i = 2 * t + (p & 1);
            if (i + 1 < m) {
                unsigned long long a = comp[i], b2 = comp[i + 1];
                if (a > b2) { comp[i] = b2; comp[i + 1] = a; }
            }
            __syncthreads();
        }
        // ---- outputs: comp[0..m) sorted ascending; rank = index ----
        const float Tf = __uint_as_float((unsigned)(comp[KK - 1] >> 32));
        const float invT = 1.0f / Tf;
        const float* trow = theta + (size_t)row * VV;
        if (t < KK) {
            unsigned long long c = comp[t];
            unsigned kbits = (unsigned)(c >> 32);
            int id = (int)(c & 0xFFFFFFFFu);
            float nv = __uint_as_float(kbits) * invT;
            xin[(size_t)row * 201 + t] = nv;
            xin[(size_t)row * 201 + 100 + t] = trow[id];
            sdist[(size_t)row * KK + t] = nv;
            idxb[(size_t)row * KK + t] = id;
        }
        if (t == 255) xin[(size_t)row * 201 + 200] = scale[row];
    } else {
        // ---------- rare fallback: radix-refine the threshold bucket ----------
#pragma unroll
        for (int j = 0; j < 8; ++j) {
            if (bn[j] < Bt) {
                int pos = atomicAdd(&sh_cnt, 1);
                if (pos < CAP)
                    comp[pos] = ((unsigned long long)kb[j] << 32) | (unsigned)(t * 8 + j);
            }
        }
        __syncthreads();
        int nless = sh_cnt;
        if (t == 0) { sh_pref = 0u; sh_kth = KK - nless; }
        __syncthreads();
        for (int p = 0; p < 4; ++p) {
            if (t < 256) hist[t] = 0u;
            __syncthreads();
            const int shift = 24 - 8 * p;
            const unsigned pref = sh_pref;
#pragma unroll
            for (int j = 0; j < 8; ++j) {
                if (bn[j] == Bt) {
                    unsigned k = kb[j];
                    bool ok = (p == 0) || ((k >> (shift + 8)) == pref);
                    if (ok) atomicAdd(&hist[(k >> shift) & 255u], 1u);
                }
            }
            __syncthreads();
            if (t == 0) {
                int kth = sh_kth;
                unsigned cum = 0;
                int b = 0;
                for (; b < 256; ++b) {
                    unsigned c = hist[b];
                    if (cum + c >= (unsigned)kth) break;
                    cum += c;
                }
                sh_pref = (pref << 8) | (unsigned)b;
                sh_kth = kth - (int)cum;
            }
            __syncthreads();
        }
        const unsigned T = sh_pref;
        const int need2 = sh_kth;
#pragma unroll
        for (int j = 0; j < 8; ++j) {
            if (bn[j] == Bt) {
                unsigned k = kb[j];
                if (k < T) {
                    int pos = atomicAdd(&sh_cnt, 1);
                    if (pos < CAP)
                        comp[pos] = ((unsigned long long)k << 32) | (unsigned)(t * 8 + j);
                } else if (k == T) {
                    int q = atomicAdd(&sh_ntie, 1);
                    if (q < 64) sh_tie[q] = t * 8 + j;
                }
            }
        }
        __syncthreads();
        if (t == 0) {
            int nl2 = sh_cnt;
            int nt = sh_ntie < 64 ? sh_ntie : 64;
            for (int i = 1; i < nt; ++i) {
                int v = sh_tie[i], j2 = i - 1;
                while (j2 >= 0 && sh_tie[j2] > v) { sh_tie[j2 + 1] = sh_tie[j2]; --j2; }
                sh_tie[j2 + 1] = v;
            }
            for (int i = 0; i < need2; ++i)
                comp[nl2 + i] = ((unsigned long long)T << 32) | (unsigned)sh_tie[i];
            sh_cnt = nl2 + need2;
        }
        __syncthreads();
        const int mm = sh_cnt;
        unsigned long long c = (t < mm) ? comp[t] : ~0ull;
        int rank = 0;
        if (t < mm) {
            for (int j = 0; j < mm; ++j) {
                unsigned long long cj = comp[j];
                rank += (cj < c) || (cj == c && j < t);
            }
            if (rank == KK - 1) sh_Tf = __uint_as_float((unsigned)(c >> 32));
        }
        __syncthreads();
        const float invT = 1.0f / sh_Tf;
        const float* trow = theta + (size_t)row * VV;
        if (t < mm && rank < KK) {
            unsigned kbits = (unsigned)(c >> 32);
            int id = (int)(c & 0xFFFFFFFFu);
            float nv = __uint_as_float(kbits) * invT;
            xin[(size_t)row * 201 + rank] = nv;
            xin[(size_t)row * 201 + 100 + rank] = trow[id];
            sdist[(size_t)row * KK + rank] = nv;
            idxb[(size_t)row * KK + rank] = id;
        }
        if (t == 255) xin[(size_t)row * 201 + 200] = scale[row];
    }
}

// ---------------------------------------------------------------------------
// Fused layers 1+2: h = relu(relu(xin@w1+b1)@w2+b2).  One block = 32 rows.
// ---------------------------------------------------------------------------
__global__ __launch_bounds__(256) void fused12_kernel(
    const float* __restrict__ xin, const float* __restrict__ w1,
    const float* __restrict__ b1, const float* __restrict__ w2,
    const float* __restrict__ b2, float* __restrict__ h)
{
    __shared__ __align__(16) float As[16][36];
    __shared__ __align__(16) float Ws[16][128];
    __shared__ __align__(16) float Hs[32][132];
    __shared__ __align__(16) float W2s[16][256];

    const int m0 = blockIdx.x * 32;
    const int t = threadIdx.x;
    const int tx = t & 31, ty = t >> 5;          // phase1: 4 cols, 4 rows

    float acc[4][4] = {};
    for (int k0 = 0; k0 < 201; k0 += 16) {
        for (int l = t; l < 512; l += 256) {
            int mm = l >> 4, kk = l & 15;
            int k = k0 + kk;
            As[kk][mm] = (k < 201) ? xin[(size_t)(m0 + mm) * 201 + k] : 0.f;
        }
        for (int l = t; l < 2048; l += 256) {
            int kk = l >> 7, c = l & 127;
            int k = k0 + kk;
            Ws[kk][c] = (k < 201) ? w1[(size_t)k * 128 + c] : 0.f;
        }
        __syncthreads();
#pragma unroll
        for (int kk = 0; kk < 16; ++kk) {
            float4 a4 = *(const float4*)&As[kk][ty * 4];
            float4 w4 = *(const float4*)&Ws[kk][tx * 4];
            float a[4] = {a4.x, a4.y, a4.z, a4.w};
            float w[4] = {w4.x, w4.y, w4.z, w4.w};
#pragma unroll
            for (int i = 0; i < 4; ++i)
#pragma unroll
                for (int j = 0; j < 4; ++j) acc[i][j] += a[i] * w[j];
        }
        __syncthreads();
    }
    {
        float4 bb = *(const float4*)&b1[tx * 4];
        float b[4] = {bb.x, bb.y, bb.z, bb.w};
#pragma unroll
        for (int i = 0; i < 4; ++i) {
            float4 v;
            v.x = fmaxf(acc[i][0] + b[0], 0.f);
            v.y = fmaxf(acc[i][1] + b[1], 0.f);
            v.z = fmaxf(acc[i][2] + b[2], 0.f);
            v.w = fmaxf(acc[i][3] + b[3], 0.f);
            *(float4*)&Hs[ty * 4 + i][tx * 4] = v;
        }
    }
    __syncthreads();

    // ---- phase 2: [32][128] @ w2[128][256] ----
    const int tx2 = t & 63, ty2 = t >> 6;        // 4 cols, 8 rows
    float acc2[8][4] = {};
    for (int c0 = 0; c0 < 8; ++c0) {
        for (int l = t; l < 4096; l += 256) {
            int kk = l >> 8, c = l & 255;
            W2s[kk][c] = w2[(size_t)(c0 * 16 + kk) * 256 + c];
        }
        __syncthreads();
#pragma unroll
        for (int k4 = 0; k4 < 4; ++k4) {
            float4 w40 = *(const float4*)&W2s[k4 * 4 + 0][tx2 * 4];
            float4 w41 = *(const float4*)&W2s[k4 * 4 + 1][tx2 * 4];
            float4 w42 = *(const float4*)&W2s[k4 * 4 + 2][tx2 * 4];
            float4 w43 = *(const float4*)&W2s[k4 * 4 + 3][tx2 * 4];
#pragma unroll
            for (int i = 0; i < 8; ++i) {
                float4 h4 = *(const float4*)&Hs[ty2 * 8 + i][c0 * 16 + k4 * 4];
                acc2[i][0] += h4.x * w40.x + h4.y * w41.x + h4.z * w42.x + h4.w * w43.x;
                acc2[i][1] += h4.x * w40.y + h4.y * w41.y + h4.z * w42.y + h4.w * w43.y;
                acc2[i][2] += h4.x * w40.z + h4.y * w41.z + h4.z * w42.z + h4.w * w43.z;
                acc2[i][3] += h4.x * w40.w + h4.y * w41.w + h4.z * w42.w + h4.w * w43.w;
            }
        }
        __syncthreads();
    }
    {
        float4 bb = *(const float4*)&b2[tx2 * 4];
#pragma unroll
        for (int i = 0; i < 8; ++i) {
            int mrow = m0 + ty2 * 8 + i;
            float4 v;
            v.x = fmaxf(acc2[i][0] + bb.x, 0.f);
            v.y = fmaxf(acc2[i][1] + bb.y, 0.f);
            v.z = fmaxf(acc2[i][2] + bb.z, 0.f);
            v.w = fmaxf(acc2[i][3] + bb.w, 0.f);
            *(float4*)&h[(size_t)mrow * 256 + tx2 * 4] = v;
        }
    }
}

// ---------------------------------------------------------------------------
// Fused layers 3+4: out4 = relu(norm(h)@w3+b3)@w4 + b4 - sdist.
// ---------------------------------------------------------------------------
__global__ __launch_bounds__(256) void fused34_kernel(
    const float* __restrict__ h, const float* __restrict__ w3,
    const float* __restrict__ b3, const float* __restrict__ w4,
    const float* __restrict__ b4, const float* __restrict__ scv,
    const float* __restrict__ shv, const float* __restrict__ sdist,
    float* __restrict__ out4)
{
    __shared__ __align__(16) float As[16][36];
    __shared__ __align__(16) float Ws[16][128];
    __shared__ __align__(16) float Hs[32][132];

    const int m0 = blockIdx.x * 32;
    const int t = threadIdx.x;
    const int tx = t & 31, ty = t >> 5;

    float acc[4][4] = {};
    for (int k0 = 0; k0 < 256; k0 += 16) {
        for (int l = t; l < 512; l += 256) {
            int mm = l >> 4, kk = l & 15;
            int k = k0 + kk, mrow = m0 + mm, b = mrow / NN;
            As[kk][mm] = h[(size_t)mrow * 256 + k] * scv[b * 256 + k] + shv[b * 256 + k];
        }
        for (int l = t; l < 2048; l += 256) {
            int kk = l >> 7, c = l & 127;
            Ws[kk][c] = w3[(size_t)(k0 + kk) * 128 + c];
        }
        __syncthreads();
#pragma unroll
        for (int kk = 0; kk < 16; ++kk) {
            float4 a4 = *(const float4*)&As[kk][ty * 4];
            float4 w4v = *(const float4*)&Ws[kk][tx * 4];
            float a[4] = {a4.x, a4.y, a4.z, a4.w};
            float w[4] = {w4v.x, w4v.y, w4v.z, w4v.w};
#pragma unroll
            for (int i = 0; i < 4; ++i)
#pragma unroll
                for (int j = 0; j < 4; ++j) acc[i][j] += a[i] * w[j];
        }
        __syncthreads();
    }
    {
        float4 bb = *(const float4*)&b3[tx * 4];
        float b[4] = {bb.x, bb.y, bb.z, bb.w};
#pragma unroll
        for (int i = 0; i < 4; ++i) {
            float4 v;
            v.x = fmaxf(acc[i][0] + b[0], 0.f);
            v.y = fmaxf(acc[i][1] + b[1], 0.f);
            v.z = fmaxf(acc[i][2] + b[2], 0.f);
            v.w = fmaxf(acc[i][3] + b[3], 0.f);
            *(float4*)&Hs[ty * 4 + i][tx * 4] = v;
        }
    }
    __syncthreads();

    // ---- phase 2: [32][128] @ w4[128][100] (cols padded to 128) ----
    float acc2[4][4] = {};
    for (int c0 = 0; c0 < 8; ++c0) {
        for (int l = t; l < 2048; l += 256) {
            int kk = l >> 7, c = l & 127;
            Ws[kk][c] = (c < KK) ? w4[(size_t)(c0 * 16 + kk) * KK + c] : 0.f;
        }
        __syncthreads();
#pragma unroll
        for (int k4 = 0; k4 < 4; ++k4) {
            float4 w40 = *(const float4*)&Ws[k4 * 4 + 0][tx * 4];
            float4 w41 = *(const float4*)&Ws[k4 * 4 + 1][tx * 4];
            float4 w42 = *(const float4*)&Ws[k4 * 4 + 2][tx * 4];
            float4 w43 = *(const float4*)&Ws[k4 * 4 + 3][tx * 4];
#pragma unroll
            for (int i = 0; i < 4; ++i) {
                float4 h4 = *(const float4*)&Hs[ty * 4 + i][c0 * 16 + k4 * 4];
                acc2[i][0] += h4.x * w40.x + h4.y * w41.x + h4.z * w42.x + h4.w * w43.x;
                acc2[i][1] += h4.x * w40.y + h4.y * w41.y + h4.z * w42.y + h4.w * w43.y;
                acc2[i][2] += h4.x * w40.z + h4.y * w41.z + h4.z * w42.z + h4.w * w43.z;
                acc2[i][3] += h4.x * w40.w + h4.y * w41.w + h4.z * w42.w + h4.w * w43.w;
            }
        }
        __syncthreads();
    }
#pragma unroll
    for (int i = 0; i < 4; ++i) {
        int mrow = m0 + ty * 4 + i;
#pragma unroll
        for (int j = 0; j < 4; ++j) {
            int c = tx * 4 + j;
            if (c < KK)
                out4[(size_t)mrow * KK + c] =
                    acc2[i][j] + b4[c] - sdist[(size_t)mrow * KK + c];
        }
    }
}

// ---------------------------------------------------------------------------
// InstanceNorm stats, two-phase.
// ---------------------------------------------------------------------------
#define NCHUNK 25
#define CHUNK (NN / NCHUNK)

__global__ __launch_bounds__(256) void stats_partial(
    const float* __restrict__ h, float* __restrict__ part)
{
    const int b = blockIdx.x, ch = blockIdx.y, c = threadIdx.x;
    const float* base = h + ((size_t)b * NN + (size_t)ch * CHUNK) * 256 + c;
    float s = 0.f, s2 = 0.f;
    for (int n = 0; n < CHUNK; ++n) {
        float v = base[(size_t)n * 256];
        s += v;
        s2 += v * v;
    }
    size_t o = (((size_t)b * NCHUNK + ch) * 256 + c) * 2;
    part[o] = s;
    part[o + 1] = s2;
}

__global__ __launch_bounds__(256) void stats_final(
    const float* __restrict__ part, const float* __restrict__ gamma,
    const float* __restrict__ beta, float* __restrict__ scv,
    float* __restrict__ shv)
{
    const int b = blockIdx.x, c = threadIdx.x;
    float s = 0.f, s2 = 0.f;
    for (int ch = 0; ch < NCHUNK; ++ch) {
        size_t o = (((size_t)b * NCHUNK + ch) * 256 + c) * 2;
        s += part[o];
        s2 += part[o + 1];
    }
    const float inv = 1.0f / (float)NN;
    float mean = s * inv;
    float var = s2 * inv - mean * mean;
    float rs = rsqrtf(var + 1e-5f);
    float sc = gamma[c] * rs;
    scv[b * 256 + c] = sc;
    shv[b * 256 + c] = beta[c] - mean * sc;
}

// ---------------------------------------------------------------------------
// Fill row with PENALTY then scatter the K computed values at idx.
// ---------------------------------------------------------------------------
__global__ __launch_bounds__(256) void scatter_kernel(
    const float* __restrict__ out4, const int* __restrict__ idxb,
    float* __restrict__ out)
{
    const int row = blockIdx.x;
    const int t = threadIdx.x;
    float4* orow = (float4*)(out + (size_t)row * VV);
    const float4 pv = make_float4(PENALTY, PENALTY, PENALTY, PENALTY);
    for (int i = t; i < VV / 4; i += 256) orow[i] = pv;
    __syncthreads();
    if (t < KK) {
        int id = idxb[(size_t)row * KK + t];
        out[(size_t)row * VV + id] = out4[(size_t)row * KK + t];
    }
}

extern "C" void kernel_launch(void* const* d_in, const int* in_sizes, int n_in,
                              void* d_out, int out_size, void* d_ws, size_t ws_size,
                              hipStream_t stream)
{
    const float* dist  = (const float*)d_in[0];
    const float* theta = (const float*)d_in[1];
    const float* scale = (const float*)d_in[2];
    const float* w1 = (const float*)d_in[3];
    const float* b1 = (const float*)d_in[4];
    const float* w2 = (const float*)d_in[5];
    const float* b2 = (const float*)d_in[6];
    const float* w3 = (const float*)d_in[7];
    const float* b3 = (const float*)d_in[8];
    const float* w4 = (const float*)d_in[9];
    const float* b4 = (const float*)d_in[10];
    const float* gamma = (const float*)d_in[11];
    const float* beta  = (const float*)d_in[12];
    float* out = (float*)d_out;

    const int M = BB * NN;  // 16000

    float* xin   = (float*)d_ws;                     // M*201
    int*   idxb  = (int*)(xin + (size_t)M * 201);    // M*100
    float* sdist = (float*)(idxb + (size_t)M * KK);  // M*100
    float* h     = sdist + (size_t)M * KK;           // M*256
    float* out4  = h + (size_t)M * 256;              // M*100
    float* scv   = out4 + (size_t)M * KK;            // 8*256
    float* shv   = scv + 8 * 256;                    // 8*256
    float* part  = shv + 8 * 256;                    // 8*25*256*2

    topk_kernel<<<M, 256, 0, stream>>>(dist, theta, scale, xin, sdist, idxb);

    fused12_kernel<<<M / 32, 256, 0, stream>>>(xin, w1, b1, w2, b2, h);

    stats_partial<<<dim3(BB, NCHUNK), 256, 0, stream>>>(h, part);
    stats_final<<<BB, 256, 0, stream>>>(part, gamma, beta, scv, shv);

    fused34_kernel<<<M / 32, 256, 0, stream>>>(h, w3, b3, w4, b4, scv, shv,
                                               sdist, out4);

    scatter_kernel<<<M, 256, 0, stream>>>(out4, idxb, out);
}

// Round 4
// 139.771 us; speedup vs baseline: 4.1789x; 2.1054x over previous
//
#include <hip/hip_runtime.h>
#include <hip/hip_bf16.h>

#define BB 8
#define NN 2000
#define VV 2000
#define KK 100
#define EMB 128
#define PENALTY -1e9f
#define NBIN 2048
#define CAP 200
#define XPAD 224   // 201 padded to 7*32

typedef __attribute__((ext_vector_type(8))) short short8;
typedef __attribute__((ext_vector_type(4))) float f32x4;

__device__ __forceinline__ unsigned short bf16rne(float f) {
    unsigned u = __float_as_uint(f);
    u += 0x7FFF + ((u >> 16) & 1);
    return (unsigned short)(u >> 16);
}
__device__ __forceinline__ float bf2f(unsigned short s) {
    return __uint_as_float((unsigned)s << 16);
}

// ---------------------------------------------------------------------------
// Kernel 0: pack weights into MFMA B-fragment layout, bf16.
// Tile = [64 lanes][8 elems]; element (lane,j) = W[kt*32+(lane>>4)*8+j][nt*16+(lane&15)]
// pw1: [7][8] tiles (K 201->224 zero-pad), pw2: [4][16], pw3: [8][8],
// pw4: [4][7] (N 100->112 zero-pad).
// ---------------------------------------------------------------------------
__global__ __launch_bounds__(256) void wpack_kernel(
    const float* __restrict__ w1, const float* __restrict__ w2,
    const float* __restrict__ w3, const float* __restrict__ w4,
    unsigned short* __restrict__ pw1, unsigned short* __restrict__ pw2,
    unsigned short* __restrict__ pw3, unsigned short* __restrict__ pw4)
{
    const int bt = blockIdx.x;   // 0..211
    const int t = threadIdx.x;
    for (int e = t; e < 512; e += 256) {
        int lane = e >> 3, j = e & 7;
        int kk = ((lane >> 4) << 3) + j;   // 0..31
        int nn = lane & 15;
        if (bt < 56) {                     // pw1: K=201, N=128
            int kt = bt >> 3, nt = bt & 7;
            int k = kt * 32 + kk, n = nt * 16 + nn;
            float f = (k < 201) ? w1[k * 128 + n] : 0.f;
            pw1[bt * 512 + e] = bf16rne(f);
        } else if (bt < 120) {             // pw2: K=128, N=256
            int bb = bt - 56, kt = bb >> 4, nt = bb & 15;
            pw2[bb * 512 + e] = bf16rne(w2[(kt * 32 + kk) * 256 + nt * 16 + nn]);
        } else if (bt < 184) {             // pw3: K=256, N=128
            int bb = bt - 120, kt = bb >> 3, nt = bb & 7;
            pw3[bb * 512 + e] = bf16rne(w3[(kt * 32 + kk) * 128 + nt * 16 + nn]);
        } else {                           // pw4: K=128, N=100->112
            int bb = bt - 184, kt = bb / 7, nt = bb % 7;
            int n = nt * 16 + nn;
            float f = (n < 100) ? w4[(kt * 32 + kk) * 100 + n] : 0.f;
            pw4[bb * 512 + e] = bf16rne(f);
        }
    }
}

// ---------------------------------------------------------------------------
// Kernel 1: per-row exact top-K (ascending, ties by index).
// Linear buckets + prefix -> bin-sorted scatter + odd-even fix-up.
// Writes xin as bf16 [M][224] (cols 201..223 never read against nonzero W).
// ---------------------------------------------------------------------------
__global__ __launch_bounds__(256) void topk_kernel(
    const float* __restrict__ dist, const float* __restrict__ theta,
    const float* __restrict__ scale,
    unsigned short* __restrict__ xin, float* __restrict__ sdist,
    int* __restrict__ idxb)
{
    __shared__ unsigned hist[NBIN];
    __shared__ unsigned long long comp[CAP];
    __shared__ unsigned wsum[4];
    __shared__ int sh_Bt, sh_m, sh_mult;
    __shared__ int sh_cnt, sh_ntie, sh_kth;
    __shared__ unsigned sh_pref;
    __shared__ int sh_tie[64];
    __shared__ float sh_Tf;

    const int row = blockIdx.x;
    const int t = threadIdx.x;
    const int lane = t & 63, wid = t >> 6;
    const float* drow = dist + (size_t)row * VV;

    unsigned kb[8];
    int bn[8];
    if (t < VV / 8) {
        const float4* d4 = (const float4*)drow;
        float4 a = d4[t * 2], b2 = d4[t * 2 + 1];
        float vv[8] = {a.x, a.y, a.z, a.w, b2.x, b2.y, b2.z, b2.w};
#pragma unroll
        for (int j = 0; j < 8; ++j) {
            kb[j] = __float_as_uint(vv[j]);
            int b = (int)(vv[j] * (float)NBIN);
            bn[j] = b < 0 ? 0 : (b > NBIN - 1 ? NBIN - 1 : b);
        }
    } else {
#pragma unroll
        for (int j = 0; j < 8; ++j) { kb[j] = 0xFFFFFFFFu; bn[j] = NBIN - 1; }
    }

    for (int i = t; i < NBIN; i += 256) hist[i] = 0u;
    if (t == 0) { sh_cnt = 0; sh_ntie = 0; sh_mult = 1; }
    __syncthreads();
#pragma unroll
    for (int j = 0; j < 8; ++j) atomicAdd(&hist[bn[j]], 1u);
    __syncthreads();

    unsigned c8[8], tot = 0;
#pragma unroll
    for (int b = 0; b < 8; ++b) { c8[b] = hist[t * 8 + b]; tot += c8[b]; }
    unsigned incl = tot;
#pragma unroll
    for (int off = 1; off < 64; off <<= 1) {
        unsigned v = __shfl_up(incl, (unsigned)off);
        if (lane >= off) incl += v;
    }
    if (lane == 63) wsum[wid] = incl;
    __syncthreads();
    unsigned woff = 0;
    for (int w = 0; w < wid; ++w) woff += wsum[w];
    const unsigned excl = woff + incl - tot;

    unsigned run = excl;
#pragma unroll
    for (int b = 0; b < 8; ++b) { unsigned cc = c8[b]; hist[t * 8 + b] = run; run += cc; }
    if (excl < KK && run >= KK) {
        unsigned cum = excl;
#pragma unroll
        for (int b = 0; b < 8; ++b) {
            if (cum + c8[b] >= KK) { sh_Bt = t * 8 + b; sh_m = (int)(cum + c8[b]); break; }
            cum += c8[b];
        }
    }
    __syncthreads();
    const int Bt = sh_Bt;
    const int m = sh_m;

    {
        int mx = 0;
#pragma unroll
        for (int b = 0; b < 8; ++b)
            if (t * 8 + b <= Bt) mx = mx > (int)c8[b] ? mx : (int)c8[b];
        if (mx > 1) atomicMax(&sh_mult, mx);
    }

    if (m <= CAP) {
#pragma unroll
        for (int j = 0; j < 8; ++j) {
            if (bn[j] <= Bt) {
                int slot = (int)atomicAdd(&hist[bn[j]], 1u);
                comp[slot] = ((unsigned long long)kb[j] << 32) | (unsigned)(t * 8 + j);
            }
        }
        __syncthreads();
        const int passes = (sh_mult > 1) ? sh_mult + 1 : 0;
        for (int p = 0; p < passes; ++p) {
            int i = 2 * t + (p & 1);
            if (i + 1 < m) {
                unsigned long long a = comp[i], b2 = comp[i + 1];
                if (a > b2) { comp[i] = b2; comp[i + 1] = a; }
            }
            __syncthreads();
        }
        const float Tf = __uint_as_float((unsigned)(comp[KK - 1] >> 32));
        const float invT = 1.0f / Tf;
        const float* trow = theta + (size_t)row * VV;
        if (t < KK) {
            unsigned long long c = comp[t];
            unsigned kbits = (unsigned)(c >> 32);
            int id = (int)(c & 0xFFFFFFFFu);
            float nv = __uint_as_float(kbits) * invT;
            xin[(size_t)row * XPAD + t] = bf16rne(nv);
            xin[(size_t)row * XPAD + 100 + t] = bf16rne(trow[id]);
            sdist[(size_t)row * KK + t] = nv;
            idxb[(size_t)row * KK + t] = id;
        }
        if (t == 255) xin[(size_t)row * XPAD + 200] = bf16rne(scale[row]);
    } else {
        // ---------- rare fallback: radix-refine the threshold bucket ----------
#pragma unroll
        for (int j = 0; j < 8; ++j) {
            if (bn[j] < Bt) {
                int pos = atomicAdd(&sh_cnt, 1);
                if (pos < CAP)
                    comp[pos] = ((unsigned long long)kb[j] << 32) | (unsigned)(t * 8 + j);
            }
        }
        __syncthreads();
        int nless = sh_cnt;
        if (t == 0) { sh_pref = 0u; sh_kth = KK - nless; }
        __syncthreads();
        for (int p = 0; p < 4; ++p) {
            if (t < 256) hist[t] = 0u;
            __syncthreads();
            const int shift = 24 - 8 * p;
            const unsigned pref = sh_pref;
#pragma unroll
            for (int j = 0; j < 8; ++j) {
                if (bn[j] == Bt) {
                    unsigned k = kb[j];
                    bool ok = (p == 0) || ((k >> (shift + 8)) == pref);
                    if (ok) atomicAdd(&hist[(k >> shift) & 255u], 1u);
                }
            }
            __syncthreads();
            if (t == 0) {
                int kth = sh_kth;
                unsigned cum = 0;
                int b = 0;
                for (; b < 256; ++b) {
                    unsigned c = hist[b];
                    if (cum + c >= (unsigned)kth) break;
                    cum += c;
                }
                sh_pref = (pref << 8) | (unsigned)b;
                sh_kth = kth - (int)cum;
            }
            __syncthreads();
        }
        const unsigned T = sh_pref;
        const int need2 = sh_kth;
#pragma unroll
        for (int j = 0; j < 8; ++j) {
            if (bn[j] == Bt) {
                unsigned k = kb[j];
                if (k < T) {
                    int pos = atomicAdd(&sh_cnt, 1);
                    if (pos < CAP)
                        comp[pos] = ((unsigned long long)k << 32) | (unsigned)(t * 8 + j);
                } else if (k == T) {
                    int q = atomicAdd(&sh_ntie, 1);
                    if (q < 64) sh_tie[q] = t * 8 + j;
                }
            }
        }
        __syncthreads();
        if (t == 0) {
            int nl2 = sh_cnt;
            int nt = sh_ntie < 64 ? sh_ntie : 64;
            for (int i = 1; i < nt; ++i) {
                int v = sh_tie[i], j2 = i - 1;
                while (j2 >= 0 && sh_tie[j2] > v) { sh_tie[j2 + 1] = sh_tie[j2]; --j2; }
                sh_tie[j2 + 1] = v;
            }
            for (int i = 0; i < need2; ++i)
                comp[nl2 + i] = ((unsigned long long)T << 32) | (unsigned)sh_tie[i];
            sh_cnt = nl2 + need2;
        }
        __syncthreads();
        const int mm = sh_cnt;
        unsigned long long c = (t < mm) ? comp[t] : ~0ull;
        int rank = 0;
        if (t < mm) {
            for (int j = 0; j < mm; ++j) {
                unsigned long long cj = comp[j];
                rank += (cj < c) || (cj == c && j < t);
            }
            if (rank == KK - 1) sh_Tf = __uint_as_float((unsigned)(c >> 32));
        }
        __syncthreads();
        const float invT = 1.0f / sh_Tf;
        const float* trow = theta + (size_t)row * VV;
        if (t < mm && rank < KK) {
            unsigned kbits = (unsigned)(c >> 32);
            int id = (int)(c & 0xFFFFFFFFu);
            float nv = __uint_as_float(kbits) * invT;
            xin[(size_t)row * XPAD + rank] = bf16rne(nv);
            xin[(size_t)row * XPAD + 100 + rank] = bf16rne(trow[id]);
            sdist[(size_t)row * KK + rank] = nv;
            idxb[(size_t)row * KK + rank] = id;
        }
        if (t == 255) xin[(size_t)row * XPAD + 200] = bf16rne(scale[row]);
    }
}

// ---------------------------------------------------------------------------
// Kernel 2: fused layers 1+2 via MFMA. Block = 64 rows, 4 waves (16 rows/wave).
// A-frags straight from global bf16; B-frags from packed weights; intermediate
// through 17KB LDS. h written bf16.
// ---------------------------------------------------------------------------
__global__ __launch_bounds__(256) void fused12_mfma(
    const unsigned short* __restrict__ xin, const unsigned short* __restrict__ pw1,
    const float* __restrict__ b1, const unsigned short* __restrict__ pw2,
    const float* __restrict__ b2, unsigned short* __restrict__ h)
{
    __shared__ unsigned short c1s[64][136];
    const int t = threadIdx.x;
    const int w = t >> 6, l = t & 63;
    const int m0 = blockIdx.x * 64;
    const int lr = l & 15, lg = l >> 4;

    // phase 1: [16 rows] x K=224 x N=128
    f32x4 acc[8] = {};
    const short8* arow = (const short8*)(xin + (size_t)(m0 + 16 * w + lr) * XPAD);
    const short8* pw1v = (const short8*)pw1;
#pragma unroll
    for (int kt = 0; kt < 7; ++kt) {
        short8 a = arow[kt * 4 + lg];
#pragma unroll
        for (int nt = 0; nt < 8; ++nt) {
            short8 b = pw1v[(kt * 8 + nt) * 64 + l];
            acc[nt] = __builtin_amdgcn_mfma_f32_16x16x32_bf16(a, b, acc[nt], 0, 0, 0);
        }
    }
#pragma unroll
    for (int nt = 0; nt < 8; ++nt) {
        int col = nt * 16 + lr;
        float bb = b1[col];
#pragma unroll
        for (int r = 0; r < 4; ++r) {
            float v = fmaxf(acc[nt][r] + bb, 0.f);
            c1s[16 * w + lg * 4 + r][col] = bf16rne(v);
        }
    }
    __syncthreads();

    // phase 2: [16 rows] x K=128 x N=256
    f32x4 acc2[16] = {};
    const short8* pw2v = (const short8*)pw2;
#pragma unroll
    for (int kt = 0; kt < 4; ++kt) {
        short8 a = *(const short8*)&c1s[16 * w + lr][kt * 32 + lg * 8];
#pragma unroll
        for (int nt = 0; nt < 16; ++nt) {
            short8 b = pw2v[(kt * 16 + nt) * 64 + l];
            acc2[nt] = __builtin_amdgcn_mfma_f32_16x16x32_bf16(a, b, acc2[nt], 0, 0, 0);
        }
    }
#pragma unroll
    for (int nt = 0; nt < 16; ++nt) {
        int col = nt * 16 + lr;
        float bb = b2[col];
#pragma unroll
        for (int r = 0; r < 4; ++r) {
            float v = fmaxf(acc2[nt][r] + bb, 0.f);
            h[(size_t)(m0 + 16 * w + lg * 4 + r) * 256 + col] = bf16rne(v);
        }
    }
}

// ---------------------------------------------------------------------------
// InstanceNorm stats (reads bf16 h), two-phase, folded affine.
// ---------------------------------------------------------------------------
#define NCHUNK 25
#define CHUNK (NN / NCHUNK)

__global__ __launch_bounds__(256) void stats_partial(
    const unsigned short* __restrict__ h, float* __restrict__ part)
{
    const int b = blockIdx.x, ch = blockIdx.y, c = threadIdx.x;
    const unsigned short* base = h + ((size_t)b * NN + (size_t)ch * CHUNK) * 256 + c;
    float s = 0.f, s2 = 0.f;
    for (int n = 0; n < CHUNK; ++n) {
        float v = bf2f(base[(size_t)n * 256]);
        s += v;
        s2 += v * v;
    }
    size_t o = (((size_t)b * NCHUNK + ch) * 256 + c) * 2;
    part[o] = s;
    part[o + 1] = s2;
}

__global__ __launch_bounds__(256) void stats_final(
    const float* __restrict__ part, const float* __restrict__ gamma,
    const float* __restrict__ beta, float* __restrict__ scv,
    float* __restrict__ shv)
{
    const int b = blockIdx.x, c = threadIdx.x;
    float s = 0.f, s2 = 0.f;
    for (int ch = 0; ch < NCHUNK; ++ch) {
        size_t o = (((size_t)b * NCHUNK + ch) * 256 + c) * 2;
        s += part[o];
        s2 += part[o + 1];
    }
    const float inv = 1.0f / (float)NN;
    float mean = s * inv;
    float var = s2 * inv - mean * mean;
    float rs = rsqrtf(var + 1e-5f);
    float sc = gamma[c] * rs;
    scv[b * 256 + c] = sc;
    shv[b * 256 + c] = beta[c] - mean * sc;
}

// ---------------------------------------------------------------------------
// Kernel 3: fused layers 3+4 + PENALTY fill + scatter. Block = 64 rows.
// InstanceNorm affine applied in-register on A-fragment load.
// ---------------------------------------------------------------------------
__global__ __launch_bounds__(256) void fused34_mfma(
    const unsigned short* __restrict__ h, const unsigned short* __restrict__ pw3,
    const float* __restrict__ b3, const unsigned short* __restrict__ pw4,
    const float* __restrict__ b4, const float* __restrict__ scv,
    const float* __restrict__ shv, const float* __restrict__ sdist,
    const int* __restrict__ idxb, float* __restrict__ out)
{
    __shared__ unsigned short c1s[64][136];
    const int t = threadIdx.x;
    const int w = t >> 6, l = t & 63;
    const int m0 = blockIdx.x * 64;
    const int lr = l & 15, lg = l >> 4;

    // fill this block's 64 output rows with PENALTY (ordered before scatter
    // by the phase-boundary __syncthreads below)
    {
        float4* o4 = (float4*)(out + (size_t)m0 * VV);
        const float4 pv = make_float4(PENALTY, PENALTY, PENALTY, PENALTY);
        for (int i = t; i < 64 * VV / 4; i += 256) o4[i] = pv;
    }

    const int myrow = m0 + 16 * w + lr;
    const int mybatch = myrow / NN;

    // phase 1: norm(h)[16 rows] x K=256 x N=128
    f32x4 acc[8] = {};
    const short8* hrow = (const short8*)(h + (size_t)myrow * 256);
    const short8* pw3v = (const short8*)pw3;
#pragma unroll
    for (int kt = 0; kt < 8; ++kt) {
        int k0 = kt * 32 + lg * 8;
        short8 hv = hrow[kt * 4 + lg];
        const float4* scp = (const float4*)(scv + mybatch * 256 + k0);
        const float4* shp = (const float4*)(shv + mybatch * 256 + k0);
        float4 sc0 = scp[0], sc1 = scp[1];
        float4 sh0 = shp[0], sh1 = shp[1];
        short8 a;
        a[0] = (short)bf16rne(fmaf(bf2f((unsigned short)hv[0]), sc0.x, sh0.x));
        a[1] = (short)bf16rne(fmaf(bf2f((unsigned short)hv[1]), sc0.y, sh0.y));
        a[2] = (short)bf16rne(fmaf(bf2f((unsigned short)hv[2]), sc0.z, sh0.z));
        a[3] = (short)bf16rne(fmaf(bf2f((unsigned short)hv[3]), sc0.w, sh0.w));
        a[4] = (short)bf16rne(fmaf(bf2f((unsigned short)hv[4]), sc1.x, sh1.x));
        a[5] = (short)bf16rne(fmaf(bf2f((unsigned short)hv[5]), sc1.y, sh1.y));
        a[6] = (short)bf16rne(fmaf(bf2f((unsigned short)hv[6]), sc1.z, sh1.z));
        a[7] = (short)bf16rne(fmaf(bf2f((unsigned short)hv[7]), sc1.w, sh1.w));
#pragma unroll
        for (int nt = 0; nt < 8; ++nt) {
            short8 b = pw3v[(kt * 8 + nt) * 64 + l];
            acc[nt] = __builtin_amdgcn_mfma_f32_16x16x32_bf16(a, b, acc[nt], 0, 0, 0);
        }
    }
#pragma unroll
    for (int nt = 0; nt < 8; ++nt) {
        int col = nt * 16 + lr;
        float bb = b3[col];
#pragma unroll
        for (int r = 0; r < 4; ++r) {
            float v = fmaxf(acc[nt][r] + bb, 0.f);
            c1s[16 * w + lg * 4 + r][col] = bf16rne(v);
        }
    }
    __syncthreads();

    // phase 2: [16 rows] x K=128 x N=112 (cols 100..111 hit zero weights)
    f32x4 acc2[7] = {};
    const short8* pw4v = (const short8*)pw4;
#pragma unroll
    for (int kt = 0; kt < 4; ++kt) {
        short8 a = *(const short8*)&c1s[16 * w + lr][kt * 32 + lg * 8];
#pragma unroll
        for (int nt = 0; nt < 7; ++nt) {
            short8 b = pw4v[(kt * 7 + nt) * 64 + l];
            acc2[nt] = __builtin_amdgcn_mfma_f32_16x16x32_bf16(a, b, acc2[nt], 0, 0, 0);
        }
    }
    // epilogue: + b4 - sdist, scatter directly from accumulators
#pragma unroll
    for (int nt = 0; nt < 7; ++nt) {
        int col = nt * 16 + lr;
        if (col < KK) {
            float bb = b4[col];
#pragma unroll
            for (int r = 0; r < 4; ++r) {
                int mrow = m0 + 16 * w + lg * 4 + r;
                float v = acc2[nt][r] + bb - sdist[(size_t)mrow * KK + col];
                int id = idxb[(size_t)mrow * KK + col];
                out[(size_t)mrow * VV + id] = v;
            }
        }
    }
}

extern "C" void kernel_launch(void* const* d_in, const int* in_sizes, int n_in,
                              void* d_out, int out_size, void* d_ws, size_t ws_size,
                              hipStream_t stream)
{
    const float* dist  = (const float*)d_in[0];
    const float* theta = (const float*)d_in[1];
    const float* scale = (const float*)d_in[2];
    const float* w1 = (const float*)d_in[3];
    const float* b1 = (const float*)d_in[4];
    const float* w2 = (const float*)d_in[5];
    const float* b2 = (const float*)d_in[6];
    const float* w3 = (const float*)d_in[7];
    const float* b3 = (const float*)d_in[8];
    const float* w4 = (const float*)d_in[9];
    const float* b4 = (const float*)d_in[10];
    const float* gamma = (const float*)d_in[11];
    const float* beta  = (const float*)d_in[12];
    float* out = (float*)d_out;

    const int M = BB * NN;  // 16000

    // workspace layout
    char* p = (char*)d_ws;
    unsigned short* xin = (unsigned short*)p;       p += (size_t)M * XPAD * 2;   // 7.17MB
    unsigned short* h   = (unsigned short*)p;       p += (size_t)M * 256 * 2;    // 8.19MB
    float* sdist = (float*)p;                       p += (size_t)M * KK * 4;     // 6.4MB
    int*   idxb  = (int*)p;                         p += (size_t)M * KK * 4;     // 6.4MB
    float* part  = (float*)p;                       p += (size_t)BB * NCHUNK * 256 * 2 * 4;
    float* scv   = (float*)p;                       p += 8 * 256 * 4;
    float* shv   = (float*)p;                       p += 8 * 256 * 4;
    unsigned short* pw1 = (unsigned short*)p;       p += 56 * 512 * 2;
    unsigned short* pw2 = (unsigned short*)p;       p += 64 * 512 * 2;
    unsigned short* pw3 = (unsigned short*)p;       p += 64 * 512 * 2;
    unsigned short* pw4 = (unsigned short*)p;       p += 28 * 512 * 2;

    wpack_kernel<<<212, 256, 0, stream>>>(w1, w2, w3, w4, pw1, pw2, pw3, pw4);

    topk_kernel<<<M, 256, 0, stream>>>(dist, theta, scale, xin, sdist, idxb);

    fused12_mfma<<<M / 64, 256, 0, stream>>>(xin, pw1, b1, pw2, b2, h);

    stats_partial<<<dim3(BB, NCHUNK), 256, 0, stream>>>(h, part);
    stats_final<<<BB, 256, 0, stream>>>(part, gamma, beta, scv, shv);

    fused34_mfma<<<M / 64, 256, 0, stream>>>(h, pw3, b3, pw4, b4, scv, shv,
                                             sdist, idxb, out);
}